// Round 1
// 6156.479 us; speedup vs baseline: 1.2172x; 1.2172x over previous
//
#include <hip/hip_runtime.h>
#include <hip/hip_bf16.h>
#include <stdint.h>

// Problem constants
#define B_   32
#define N_   2048   // n_stock
#define F_   1024   // in_features
#define HS_  8192   // 4*N
#define HF_  4096   // 4*F
#define OUT_ 1024

typedef __bf16 bf16x8 __attribute__((ext_vector_type(8)));
typedef float  f32x4  __attribute__((ext_vector_type(4)));
typedef unsigned long long u64;

__device__ __forceinline__ float bf2f(unsigned short u) {
  union { unsigned int i; float f; } c; c.i = ((unsigned int)u) << 16; return c.f;
}
__device__ __forceinline__ unsigned short f2bf(float f) {
  union { float f; unsigned int i; } c; c.f = f;
  unsigned int x = c.i;
  return (unsigned short)((x + 0x7FFFu + ((x >> 16) & 1u)) >> 16);  // RNE
}

// ---------------------------------------------------------------------------
// 0. f32 -> bf16 bulk convert (weights). n multiple of 8.
// ---------------------------------------------------------------------------
__global__ __launch_bounds__(256) void f2bf_kernel(
    const float* __restrict__ in, unsigned short* __restrict__ out, int n) {
  int i = (blockIdx.x * 256 + threadIdx.x) * 8;
  if (i >= n) return;
  const float4 a = ((const float4*)(in + i))[0];
  const float4 b = ((const float4*)(in + i))[1];
  unsigned int w0 = (unsigned int)f2bf(a.x) | ((unsigned int)f2bf(a.y) << 16);
  unsigned int w1 = (unsigned int)f2bf(a.z) | ((unsigned int)f2bf(a.w) << 16);
  unsigned int w2 = (unsigned int)f2bf(b.x) | ((unsigned int)f2bf(b.y) << 16);
  unsigned int w3 = (unsigned int)f2bf(b.z) | ((unsigned int)f2bf(b.w) << 16);
  *(uint4*)(out + i) = make_uint4(w0, w1, w2, w3);
}

// ---------------------------------------------------------------------------
// 1. Transpose x [B,N,F] -> xm [B,F,N]  (f32, LDS 64x64 tile, +1 pad)
// ---------------------------------------------------------------------------
__global__ __launch_bounds__(256) void transpose_xk(
    const float* __restrict__ x, float* __restrict__ xm) {
  __shared__ float tile[64][65];
  const int b  = blockIdx.z;
  const int n0 = blockIdx.y * 64;
  const int f0 = blockIdx.x * 64;
  const int tx = threadIdx.x & 63;
  const int ty = threadIdx.x >> 6;
  const float* xp = x + ((size_t)b * N_ + n0) * F_ + f0;
  #pragma unroll
  for (int r = 0; r < 16; ++r) {
    int n = ty + r * 4;
    tile[tx][n] = xp[(size_t)n * F_ + tx];   // tile[f][n]
  }
  __syncthreads();
  float* xmp = xm + ((size_t)b * F_ + f0) * N_ + n0;
  #pragma unroll
  for (int r = 0; r < 16; ++r) {
    int f = ty + r * 4;
    xmp[(size_t)f * N_ + tx] = tile[f][tx];
  }
}

// ---------------------------------------------------------------------------
// 2. Stable argsort per (b,f) row: ONE ROW PER WAVE, keys in registers.
//    u64 key = (order-preserving f32 map << 32) | idx  -> stable ascending.
//    Blocked mapping: logical index i = lane*32 + e, e = 0..31 in registers.
//      j <= 16 : in-register compare-exchange (static indices, no LDS)
//      j >= 32 : __shfl_xor cross-lane exchange (no barriers)
//    f32 value is recovered bit-exactly from key's upper 32 bits, so no vals[].
//    LDS used only for the final inv/value scatter (per-wave private region).
// ---------------------------------------------------------------------------
__device__ __forceinline__ void ce_(u64 &a, u64 &b, bool up) {
  if ((a > b) == up) { u64 t = a; a = b; b = t; }
}

template <int J>
__device__ __forceinline__ void reg_stage(u64 key[32], int i0, int k) {
  #pragma unroll
  for (int e = 0; e < 32; ++e) {
    if ((e & J) == 0) {
      const int f = e | J;
      const bool up = (((i0 + e) & k) == 0);
      ce_(key[e], key[f], up);
    }
  }
}

__device__ __forceinline__ void xlane_stage(u64 key[32], int lane, int m, int k) {
  // j = m*32 >= 32, k >= 64  ->  direction uniform over e, agreed by both partners
  const bool up    = (((lane << 5) & k) == 0);
  const bool lower = ((lane & m) == 0);
  const bool keep_min = (up == lower);
  #pragma unroll
  for (int e = 0; e < 32; ++e) {
    u64 a = key[e];
    u64 b = __shfl_xor(a, m, 64);
    key[e] = ((a < b) == keep_min) ? a : b;
  }
}

__global__ __launch_bounds__(256) void sort_kernel(
    const float* __restrict__ xm,
    unsigned short* __restrict__ xs,
    unsigned short* __restrict__ inv) {
  __shared__ __align__(16) unsigned short sval[4][N_];   // 16 KB (bf16, original order)
  __shared__ __align__(16) unsigned short sinv[4][N_];   // 16 KB (sorted pos per orig idx)
  const int t    = threadIdx.x;
  const int w    = t >> 6;
  const int lane = t & 63;
  const int row  = blockIdx.x * 4 + w;
  const size_t rb = (size_t)row * N_;
  const int i0   = lane * 32;

  // load 32 contiguous f32, build sortable keys
  u64 key[32];
  const float4* rp = (const float4*)(xm + rb + i0);
  #pragma unroll
  for (int q = 0; q < 8; ++q) {
    const float4 v = rp[q];
    const float fv[4] = {v.x, v.y, v.z, v.w};
    #pragma unroll
    for (int e = 0; e < 4; ++e) {
      union { float f; unsigned int i; } c; c.f = fv[e];
      unsigned int m = (c.i & 0x80000000u) ? ~c.i : (c.i | 0x80000000u);
      key[q * 4 + e] = (((u64)m) << 32) | (u64)(i0 + q * 4 + e);
    }
  }

  // bitonic network on logical index i = lane*32 + e
  #pragma unroll 1
  for (int k = 2; k <= N_; k <<= 1) {
    #pragma unroll 1
    for (int j = k >> 1; j >= 32; j >>= 1)
      xlane_stage(key, lane, j >> 5, k);
    if (k >= 32) {
      reg_stage<16>(key, i0, k);
      reg_stage<8>(key, i0, k);
      reg_stage<4>(key, i0, k);
      reg_stage<2>(key, i0, k);
      reg_stage<1>(key, i0, k);
    } else if (k == 16) {
      reg_stage<8>(key, i0, k);
      reg_stage<4>(key, i0, k);
      reg_stage<2>(key, i0, k);
      reg_stage<1>(key, i0, k);
    } else if (k == 8) {
      reg_stage<4>(key, i0, k);
      reg_stage<2>(key, i0, k);
      reg_stage<1>(key, i0, k);
    } else if (k == 4) {
      reg_stage<2>(key, i0, k);
      reg_stage<1>(key, i0, k);
    } else {
      reg_stage<1>(key, i0, k);
    }
  }

  // scatter: reconstruct original-order values (bf16) + inverse permutation
  #pragma unroll
  for (int e = 0; e < 32; ++e) {
    const unsigned int orig = (unsigned int)key[e] & (N_ - 1);
    const unsigned int m32  = (unsigned int)(key[e] >> 32);
    const unsigned int ci   = (m32 & 0x80000000u) ? (m32 & 0x7FFFFFFFu) : ~m32;
    union { unsigned int i; float f; } c; c.i = ci;
    sval[w][orig] = f2bf(c.f);
    sinv[w][orig] = (unsigned short)(i0 + e);
  }
  __syncthreads();

  // xs[i] = vals[inv[i]] (scatter-by-argsort == gather-by-inverse); emit inv
  unsigned short* xsr  = xs  + rb;
  unsigned short* invr = inv + rb;
  #pragma unroll
  for (int q = 0; q < 4; ++q) {
    const int base = q * 512 + lane * 8;
    const uint4 ivv = *(const uint4*)(&sinv[w][base]);
    const unsigned int iw[4] = {ivv.x, ivv.y, ivv.z, ivv.w};
    unsigned int pw[4];
    #pragma unroll
    for (int p = 0; p < 4; ++p) {
      const unsigned int lo = sval[w][iw[p] & 0xFFFFu];
      const unsigned int hi = sval[w][(iw[p] >> 16) & 0xFFFFu];
      pw[p] = lo | (hi << 16);
    }
    *(uint4*)(xsr + base)  = make_uint4(pw[0], pw[1], pw[2], pw[3]);
    *(uint4*)(invr + base) = ivv;
  }
}

// ---------------------------------------------------------------------------
// 3. NT GEMM (m97 recipe): C[M,N] = A[M,K] * Bt[N,K]^T, bf16 in, fp32 acc.
//    128x128 tile, BK=64, global_load_lds(16B), 16x16x32 bf16 MFMA.
//    EPI: 0 = bias+relu -> bf16, 1 = bias+skip(bf16) -> bf16, 2 = bias -> f32
// ---------------------------------------------------------------------------
template <int EPI>
__global__ __launch_bounds__(256) void gemm_bt(
    const unsigned short* __restrict__ A,
    const unsigned short* __restrict__ Bt,
    const float* __restrict__ bias,
    const unsigned short* __restrict__ skip,
    void* __restrict__ Cv,
    int N, int K) {
  __shared__ __align__(16) unsigned short As[128 * 64];
  __shared__ __align__(16) unsigned short Bs[128 * 64];
  const int n0   = blockIdx.x * 128;
  const int m0   = blockIdx.y * 128;
  const int t    = threadIdx.x;
  const int lane = t & 63;
  const int wave = t >> 6;
  const int wm = (wave >> 1) * 64;
  const int wn = (wave & 1) * 64;
  const int lr = lane & 15;
  const int lk = (lane >> 4) * 8;

  f32x4 acc[4][4];
  #pragma unroll
  for (int i = 0; i < 4; ++i)
    #pragma unroll
    for (int j = 0; j < 4; ++j)
      acc[i][j] = (f32x4){0.f, 0.f, 0.f, 0.f};

  const unsigned short* aB = A  + (size_t)m0 * K;
  const unsigned short* bB = Bt + (size_t)n0 * K;

  for (int k0 = 0; k0 < K; k0 += 64) {
    #pragma unroll
    for (int i = 0; i < 4; ++i) {
      const int cbase = i * 256 + wave * 64;       // wave-uniform LDS base chunk
      const int chunk = cbase + lane;
      const int row = chunk >> 3;
      const int col = (chunk & 7) << 3;            // element offset (8 bf16 = 16B)
      __builtin_amdgcn_global_load_lds(
          (const __attribute__((address_space(1))) void*)(aB + (size_t)row * K + (k0 + col)),
          (__attribute__((address_space(3))) void*)(As + (size_t)cbase * 8), 16, 0, 0);
      __builtin_amdgcn_global_load_lds(
          (const __attribute__((address_space(1))) void*)(bB + (size_t)row * K + (k0 + col)),
          (__attribute__((address_space(3))) void*)(Bs + (size_t)cbase * 8), 16, 0, 0);
    }
    __syncthreads();
    #pragma unroll
    for (int kk = 0; kk < 64; kk += 32) {
      bf16x8 af[4], bv[4];
      #pragma unroll
      for (int i = 0; i < 4; ++i)
        af[i] = *(const bf16x8*)(As + (wm + i * 16 + lr) * 64 + kk + lk);
      #pragma unroll
      for (int j = 0; j < 4; ++j)
        bv[j] = *(const bf16x8*)(Bs + (wn + j * 16 + lr) * 64 + kk + lk);
      #pragma unroll
      for (int i = 0; i < 4; ++i)
        #pragma unroll
        for (int j = 0; j < 4; ++j)
          acc[i][j] = __builtin_amdgcn_mfma_f32_16x16x32_bf16(af[i], bv[j], acc[i][j], 0, 0, 0);
    }
    __syncthreads();
  }

  // epilogue: C/D layout col=lane&15, row=(lane>>4)*4+reg  [m89-verified]
  #pragma unroll
  for (int j = 0; j < 4; ++j) {
    const int gn = n0 + wn + j * 16 + lr;
    const float bvf = bias[gn];
    #pragma unroll
    for (int i = 0; i < 4; ++i) {
      const int gm = m0 + wm + i * 16 + (lane >> 4) * 4;
      #pragma unroll
      for (int r = 0; r < 4; ++r) {
        float v = acc[i][j][r] + bvf;
        if (EPI == 0) v = v > 0.f ? v : 0.f;
        const size_t off = (size_t)(gm + r) * N + gn;
        if (EPI == 1) v += bf2f(skip[off]);
        if (EPI == 2) ((float*)Cv)[off] = v;
        else          ((unsigned short*)Cv)[off] = f2bf(v);
      }
    }
  }
}

// ---------------------------------------------------------------------------
// 4. Unpermute + transpose: Y2[b, inv[b,f,j], f] = Y[b, f, j]   (bf16)
// ---------------------------------------------------------------------------
__global__ __launch_bounds__(256) void unpermute_kernel(
    const unsigned short* __restrict__ Y,
    const unsigned short* __restrict__ inv,
    unsigned short* __restrict__ Y2) {
  __shared__ unsigned short ot[N_][16];      // 64 KB, col swizzle (fl + (n>>2)) & 15
  const int b  = blockIdx.x >> 6;            // F/16 = 64 slabs per batch
  const int f0 = (blockIdx.x & 63) * 16;
  const int t  = threadIdx.x;
  const size_t rbase = ((size_t)b * F_ + f0) * N_;

  for (int fl = 0; fl < 16; ++fl) {
    const uint4 yv = ((const uint4*)(Y   + rbase + (size_t)fl * N_))[t];
    const uint4 iv = ((const uint4*)(inv + rbase + (size_t)fl * N_))[t];
    unsigned int yw[4] = {yv.x, yv.y, yv.z, yv.w};
    unsigned int iw[4] = {iv.x, iv.y, iv.z, iv.w};
    #pragma unroll
    for (int e = 0; e < 8; ++e) {
      unsigned short yy = (unsigned short)(yw[e >> 1] >> ((e & 1) * 16));
      int n = (int)(unsigned short)(iw[e >> 1] >> ((e & 1) * 16));
      ot[n][(fl + (n >> 2)) & 15] = yy;
    }
  }
  __syncthreads();
  unsigned short* o = Y2 + (size_t)b * N_ * F_ + f0;
  for (int it = 0; it < 8; ++it) {
    int n = it * 256 + t;
    unsigned short tmp[16];
    #pragma unroll
    for (int fl = 0; fl < 16; ++fl) tmp[fl] = ot[n][(fl + (n >> 2)) & 15];
    unsigned int pw[8];
    #pragma unroll
    for (int q = 0; q < 8; ++q)
      pw[q] = (unsigned int)tmp[2 * q] | (((unsigned int)tmp[2 * q + 1]) << 16);
    uint4* dst = (uint4*)(o + (size_t)n * F_);
    dst[0] = make_uint4(pw[0], pw[1], pw[2], pw[3]);
    dst[1] = make_uint4(pw[4], pw[5], pw[6], pw[7]);
  }
}

// ---------------------------------------------------------------------------
extern "C" void kernel_launch(void* const* d_in, const int* in_sizes, int n_in,
                              void* d_out, int out_size, void* d_ws, size_t ws_size,
                              hipStream_t stream) {
  const float* x    = (const float*)d_in[0];
  const float* sw1f = (const float*)d_in[1];
  const float* sb1  = (const float*)d_in[2];
  const float* sw2f = (const float*)d_in[3];
  const float* sb2  = (const float*)d_in[4];
  const float* fw1f = (const float*)d_in[5];
  const float* fb1  = (const float*)d_in[6];
  const float* fw2f = (const float*)d_in[7];
  const float* fb2  = (const float*)d_in[8];
  float* outp = (float*)d_out;

  const size_t E = (size_t)B_ * F_ * N_;     // 67,108,864 elements
  // workspace layout (~730 MB)
  float*          xm  = (float*)d_ws;                     // E f32      [0, 256MB)
  unsigned short* xs  = (unsigned short*)(xm + E);        // E bf16     [256, 384)
  unsigned short* inv = xs + E;                           // E u16      [384, 512)
  unsigned short* wb  = inv + E;                          // weights bf16
  unsigned short* wsw1 = wb;                              // 8192*2048
  unsigned short* wsw2 = wsw1 + (size_t)HS_ * N_;         // 2048*8192
  unsigned short* wfw1 = wsw2 + (size_t)N_ * HS_;         // 4096*1024
  unsigned short* wfw2 = wfw1 + (size_t)HF_ * F_;         // 1024*4096
  unsigned short* Hc   = wfw2 + (size_t)OUT_ * HF_;       // 67.1M bf16 (134 MB) chunk hidden
  unsigned short* Y    = (unsigned short*)xm;             // reuse xm region (bf16)
  unsigned short* Y2   = xs;                              // reuse xs region

  // 0. convert weights f32 -> bf16
  f2bf_kernel<<<(HS_ * N_) / 2048, 256, 0, stream>>>(sw1f, wsw1, HS_ * N_);
  f2bf_kernel<<<(N_ * HS_) / 2048, 256, 0, stream>>>(sw2f, wsw2, N_ * HS_);
  f2bf_kernel<<<(HF_ * F_) / 2048, 256, 0, stream>>>(fw1f, wfw1, HF_ * F_);
  f2bf_kernel<<<(OUT_ * HF_) / 2048, 256, 0, stream>>>(fw2f, wfw2, OUT_ * HF_);

  // 1. transpose x -> xm (f32)
  transpose_xk<<<dim3(F_ / 64, N_ / 64, B_), 256, 0, stream>>>(x, xm);
  // 2. stable sort rows -> xs (bf16), inv (u16); one row per wave, 4 rows/block
  sort_kernel<<<dim3(B_ * F_ / 4), 256, 0, stream>>>(xm, xs, inv);

  // 3+4. sorted MLP, chunked over rows (4 x 8192 rows)
  for (int c = 0; c < 4; ++c) {
    const size_t ro = (size_t)c * 8192;
    gemm_bt<0><<<dim3(HS_ / 128, 8192 / 128), 256, 0, stream>>>(
        xs + ro * N_, wsw1, sb1, nullptr, Hc, HS_, N_);
    gemm_bt<1><<<dim3(N_ / 128, 8192 / 128), 256, 0, stream>>>(
        Hc, wsw2, sb2, xs + ro * N_, Y + ro * N_, N_, HS_);
  }

  // 5. Y2[b, inv[j], f] = Y[b, f, j]
  unpermute_kernel<<<dim3(B_ * (F_ / 16)), 256, 0, stream>>>(Y, inv, Y2);

  // 6+7. feature MLP, chunked over rows (4 x 16384 rows)
  for (int c = 0; c < 4; ++c) {
    const size_t ro = (size_t)c * 16384;
    gemm_bt<0><<<dim3(HF_ / 128, 16384 / 128), 256, 0, stream>>>(
        Y2 + ro * F_, wfw1, fb1, nullptr, Hc, HF_, F_);
    gemm_bt<2><<<dim3(OUT_ / 128, 16384 / 128), 256, 0, stream>>>(
        Hc, wfw2, fb2, nullptr, (void*)(outp + ro * OUT_), OUT_, HF_);
  }
}

// Round 2
// 5977.024 us; speedup vs baseline: 1.2538x; 1.0300x over previous
//
#include <hip/hip_runtime.h>
#include <hip/hip_bf16.h>
#include <stdint.h>

// Problem constants
#define B_   32
#define N_   2048   // n_stock
#define F_   1024   // in_features
#define HS_  8192   // 4*N
#define HF_  4096   // 4*F
#define OUT_ 1024

typedef __bf16 bf16x8 __attribute__((ext_vector_type(8)));
typedef float  f32x4  __attribute__((ext_vector_type(4)));
typedef unsigned long long u64;

__device__ __forceinline__ float bf2f(unsigned short u) {
  union { unsigned int i; float f; } c; c.i = ((unsigned int)u) << 16; return c.f;
}
__device__ __forceinline__ unsigned short f2bf(float f) {
  union { float f; unsigned int i; } c; c.f = f;
  unsigned int x = c.i;
  return (unsigned short)((x + 0x7FFFu + ((x >> 16) & 1u)) >> 16);  // RNE
}

// ---------------------------------------------------------------------------
// 0. f32 -> bf16 bulk convert (weights). n multiple of 8.
// ---------------------------------------------------------------------------
__global__ __launch_bounds__(256) void f2bf_kernel(
    const float* __restrict__ in, unsigned short* __restrict__ out, int n) {
  int i = (blockIdx.x * 256 + threadIdx.x) * 8;
  if (i >= n) return;
  const float4 a = ((const float4*)(in + i))[0];
  const float4 b = ((const float4*)(in + i))[1];
  unsigned int w0 = (unsigned int)f2bf(a.x) | ((unsigned int)f2bf(a.y) << 16);
  unsigned int w1 = (unsigned int)f2bf(a.z) | ((unsigned int)f2bf(a.w) << 16);
  unsigned int w2 = (unsigned int)f2bf(b.x) | ((unsigned int)f2bf(b.y) << 16);
  unsigned int w3 = (unsigned int)f2bf(b.z) | ((unsigned int)f2bf(b.w) << 16);
  *(uint4*)(out + i) = make_uint4(w0, w1, w2, w3);
}

// ---------------------------------------------------------------------------
// 1. Transpose x [B,N,F] -> xm [B,F,N]  (f32, LDS 64x64 tile, +1 pad)
// ---------------------------------------------------------------------------
__global__ __launch_bounds__(256) void transpose_xk(
    const float* __restrict__ x, float* __restrict__ xm) {
  __shared__ float tile[64][65];
  const int b  = blockIdx.z;
  const int n0 = blockIdx.y * 64;
  const int f0 = blockIdx.x * 64;
  const int tx = threadIdx.x & 63;
  const int ty = threadIdx.x >> 6;
  const float* xp = x + ((size_t)b * N_ + n0) * F_ + f0;
  #pragma unroll
  for (int r = 0; r < 16; ++r) {
    int n = ty + r * 4;
    tile[tx][n] = xp[(size_t)n * F_ + tx];   // tile[f][n]
  }
  __syncthreads();
  float* xmp = xm + ((size_t)b * F_ + f0) * N_ + n0;
  #pragma unroll
  for (int r = 0; r < 16; ++r) {
    int f = ty + r * 4;
    xmp[(size_t)f * N_ + tx] = tile[f][tx];
  }
}

// ---------------------------------------------------------------------------
// 2. Stable argsort per (b,f) row: ONE ROW PER WAVE, keys in registers.
//    u64 key = (order-preserving f32 map << 32) | idx  -> stable ascending.
//    Blocked mapping: logical index i = lane*32 + e.
//    Levels k=2..16: fully static, direction compile-time ((e&K)==0 since
//    (lane*32)&K == 0).  Levels k>=32: direction lane-uniform per level.
//    Epilogue: xs[orig] = xm[s] (the lane's OWN loaded value at slot e),
//    so one u32 LDS scatter (val16<<16|s) + linear vectorized read-back.
//    No __syncthreads at all (per-wave private LDS regions).
// ---------------------------------------------------------------------------
template <int K, int J>
__device__ __forceinline__ void reg_stage_ct(u64 key[32]) {
  #pragma unroll
  for (int e = 0; e < 32; ++e) {
    if ((e & J) == 0) {
      const int f = e | J;
      const bool up = ((e & K) == 0);          // compile-time
      u64 a = key[e], b = key[f];
      if ((a > b) == up) { key[e] = b; key[f] = a; }
    }
  }
}

template <int J>
__device__ __forceinline__ void reg_stage_u(u64 key[32], bool up) {
  #pragma unroll
  for (int e = 0; e < 32; ++e) {
    if ((e & J) == 0) {
      const int f = e | J;
      u64 a = key[e], b = key[f];
      if ((a > b) == up) { key[e] = b; key[f] = a; }
    }
  }
}

__device__ __forceinline__ void xlane_stage(u64 key[32], int m, bool up) {
  const bool lower = ((__lane_id() & m) == 0);
  const bool keep_min = (up == lower);
  #pragma unroll
  for (int e = 0; e < 32; ++e) {
    u64 a = key[e];
    u64 b = __shfl_xor(a, m, 64);
    key[e] = ((a < b) == keep_min) ? a : b;
  }
}

__global__ __launch_bounds__(256, 4) void sort_kernel(
    const float* __restrict__ xm,
    unsigned short* __restrict__ xs,
    unsigned short* __restrict__ inv) {
  __shared__ __align__(16) unsigned int sbuf[4][N_];   // 32 KB, per-wave private
  const int t    = threadIdx.x;
  const int w    = t >> 6;
  const int lane = t & 63;
  const int row  = blockIdx.x * 4 + w;
  const size_t rb = (size_t)row * N_;
  const int i0   = lane * 32;

  // load 32 contiguous f32; keep bf16 values packed in regs; build sort keys
  u64 key[32];
  unsigned int vbf[16];
  const float4* rp = (const float4*)(xm + rb + i0);
  #pragma unroll
  for (int q = 0; q < 8; ++q) {
    const float4 v = rp[q];
    vbf[2 * q]     = (unsigned int)f2bf(v.x) | ((unsigned int)f2bf(v.y) << 16);
    vbf[2 * q + 1] = (unsigned int)f2bf(v.z) | ((unsigned int)f2bf(v.w) << 16);
    const float fv[4] = {v.x, v.y, v.z, v.w};
    #pragma unroll
    for (int e = 0; e < 4; ++e) {
      union { float f; unsigned int i; } c; c.f = fv[e];
      unsigned int m = (c.i & 0x80000000u) ? ~c.i : (c.i | 0x80000000u);
      key[q * 4 + e] = (((u64)m) << 32) | (u64)(i0 + q * 4 + e);
    }
  }

  // ---- levels k = 2..16 : fully static, compile-time directions ----
  reg_stage_ct<2, 1>(key);
  reg_stage_ct<4, 2>(key);  reg_stage_ct<4, 1>(key);
  reg_stage_ct<8, 4>(key);  reg_stage_ct<8, 2>(key);  reg_stage_ct<8, 1>(key);
  reg_stage_ct<16, 8>(key); reg_stage_ct<16, 4>(key);
  reg_stage_ct<16, 2>(key); reg_stage_ct<16, 1>(key);

  // ---- levels k = 32..2048 : direction lane-uniform per level ----
  #pragma unroll 1
  for (int k = 32; k <= N_; k <<= 1) {
    const bool up = ((i0 & k) == 0);
    #pragma unroll 1
    for (int m = k >> 6; m >= 1; m >>= 1)    // empty for k=32
      xlane_stage(key, m, up);
    reg_stage_u<16>(key, up);
    reg_stage_u<8>(key, up);
    reg_stage_u<4>(key, up);
    reg_stage_u<2>(key, up);
    reg_stage_u<1>(key, up);
  }

  // ---- epilogue: scatter (val16<<16 | s) to index orig; no gather ----
  #pragma unroll
  for (int e = 0; e < 32; ++e) {
    const unsigned int orig  = (unsigned int)key[e] & (N_ - 1);
    const unsigned int val16 = (vbf[e >> 1] >> ((e & 1) * 16)) & 0xFFFFu;
    sbuf[w][orig] = (val16 << 16) | (unsigned int)(i0 + e);
  }

  // linear vectorized read-back (compiler inserts lgkmcnt; same-wave dep only)
  const unsigned int* sb = sbuf[w];
  unsigned int* xs32  = (unsigned int*)(xs + rb);
  unsigned int* inv32 = (unsigned int*)(inv + rb);
  #pragma unroll
  for (int q = 0; q < 8; ++q) {
    const int w0 = q * 256 + lane * 4;       // 4 consecutive words, 16B/lane
    const uint4 W = *(const uint4*)(sb + w0);
    uint2 xw, iw;
    xw.x = (W.x >> 16) | (W.y & 0xFFFF0000u);
    xw.y = (W.z >> 16) | (W.w & 0xFFFF0000u);
    iw.x = (W.x & 0xFFFFu) | (W.y << 16);
    iw.y = (W.z & 0xFFFFu) | (W.w << 16);
    *(uint2*)(xs32  + (w0 >> 1)) = xw;
    *(uint2*)(inv32 + (w0 >> 1)) = iw;
  }
}

// ---------------------------------------------------------------------------
// 3. NT GEMM (m97 recipe): C[M,N] = A[M,K] * Bt[N,K]^T, bf16 in, fp32 acc.
//    128x128 tile, BK=64, global_load_lds(16B), 16x16x32 bf16 MFMA.
//    EPI: 0 = bias+relu -> bf16, 1 = bias+skip(bf16) -> bf16, 2 = bias -> f32
// ---------------------------------------------------------------------------
template <int EPI>
__global__ __launch_bounds__(256) void gemm_bt(
    const unsigned short* __restrict__ A,
    const unsigned short* __restrict__ Bt,
    const float* __restrict__ bias,
    const unsigned short* __restrict__ skip,
    void* __restrict__ Cv,
    int N, int K) {
  __shared__ __align__(16) unsigned short As[128 * 64];
  __shared__ __align__(16) unsigned short Bs[128 * 64];
  const int n0   = blockIdx.x * 128;
  const int m0   = blockIdx.y * 128;
  const int t    = threadIdx.x;
  const int lane = t & 63;
  const int wave = t >> 6;
  const int wm = (wave >> 1) * 64;
  const int wn = (wave & 1) * 64;
  const int lr = lane & 15;
  const int lk = (lane >> 4) * 8;

  f32x4 acc[4][4];
  #pragma unroll
  for (int i = 0; i < 4; ++i)
    #pragma unroll
    for (int j = 0; j < 4; ++j)
      acc[i][j] = (f32x4){0.f, 0.f, 0.f, 0.f};

  const unsigned short* aB = A  + (size_t)m0 * K;
  const unsigned short* bB = Bt + (size_t)n0 * K;

  for (int k0 = 0; k0 < K; k0 += 64) {
    #pragma unroll
    for (int i = 0; i < 4; ++i) {
      const int cbase = i * 256 + wave * 64;       // wave-uniform LDS base chunk
      const int chunk = cbase + lane;
      const int row = chunk >> 3;
      const int col = (chunk & 7) << 3;            // element offset (8 bf16 = 16B)
      __builtin_amdgcn_global_load_lds(
          (const __attribute__((address_space(1))) void*)(aB + (size_t)row * K + (k0 + col)),
          (__attribute__((address_space(3))) void*)(As + (size_t)cbase * 8), 16, 0, 0);
      __builtin_amdgcn_global_load_lds(
          (const __attribute__((address_space(1))) void*)(bB + (size_t)row * K + (k0 + col)),
          (__attribute__((address_space(3))) void*)(Bs + (size_t)cbase * 8), 16, 0, 0);
    }
    __syncthreads();
    #pragma unroll
    for (int kk = 0; kk < 64; kk += 32) {
      bf16x8 af[4], bv[4];
      #pragma unroll
      for (int i = 0; i < 4; ++i)
        af[i] = *(const bf16x8*)(As + (wm + i * 16 + lr) * 64 + kk + lk);
      #pragma unroll
      for (int j = 0; j < 4; ++j)
        bv[j] = *(const bf16x8*)(Bs + (wn + j * 16 + lr) * 64 + kk + lk);
      #pragma unroll
      for (int i = 0; i < 4; ++i)
        #pragma unroll
        for (int j = 0; j < 4; ++j)
          acc[i][j] = __builtin_amdgcn_mfma_f32_16x16x32_bf16(af[i], bv[j], acc[i][j], 0, 0, 0);
    }
    __syncthreads();
  }

  // epilogue: C/D layout col=lane&15, row=(lane>>4)*4+reg  [m89-verified]
  #pragma unroll
  for (int j = 0; j < 4; ++j) {
    const int gn = n0 + wn + j * 16 + lr;
    const float bvf = bias[gn];
    #pragma unroll
    for (int i = 0; i < 4; ++i) {
      const int gm = m0 + wm + i * 16 + (lane >> 4) * 4;
      #pragma unroll
      for (int r = 0; r < 4; ++r) {
        float v = acc[i][j][r] + bvf;
        if (EPI == 0) v = v > 0.f ? v : 0.f;
        const size_t off = (size_t)(gm + r) * N + gn;
        if (EPI == 1) v += bf2f(skip[off]);
        if (EPI == 2) ((float*)Cv)[off] = v;
        else          ((unsigned short*)Cv)[off] = f2bf(v);
      }
    }
  }
}

// ---------------------------------------------------------------------------
// 4. Unpermute + transpose: Y2[b, inv[b,f,j], f] = Y[b, f, j]   (bf16)
// ---------------------------------------------------------------------------
__global__ __launch_bounds__(256) void unpermute_kernel(
    const unsigned short* __restrict__ Y,
    const unsigned short* __restrict__ inv,
    unsigned short* __restrict__ Y2) {
  __shared__ unsigned short ot[N_][16];      // 64 KB, col swizzle (fl + (n>>2)) & 15
  const int b  = blockIdx.x >> 6;            // F/16 = 64 slabs per batch
  const int f0 = (blockIdx.x & 63) * 16;
  const int t  = threadIdx.x;
  const size_t rbase = ((size_t)b * F_ + f0) * N_;

  for (int fl = 0; fl < 16; ++fl) {
    const uint4 yv = ((const uint4*)(Y   + rbase + (size_t)fl * N_))[t];
    const uint4 iv = ((const uint4*)(inv + rbase + (size_t)fl * N_))[t];
    unsigned int yw[4] = {yv.x, yv.y, yv.z, yv.w};
    unsigned int iw[4] = {iv.x, iv.y, iv.z, iv.w};
    #pragma unroll
    for (int e = 0; e < 8; ++e) {
      unsigned short yy = (unsigned short)(yw[e >> 1] >> ((e & 1) * 16));
      int n = (int)(unsigned short)(iw[e >> 1] >> ((e & 1) * 16));
      ot[n][(fl + (n >> 2)) & 15] = yy;
    }
  }
  __syncthreads();
  unsigned short* o = Y2 + (size_t)b * N_ * F_ + f0;
  for (int it = 0; it < 8; ++it) {
    int n = it * 256 + t;
    unsigned short tmp[16];
    #pragma unroll
    for (int fl = 0; fl < 16; ++fl) tmp[fl] = ot[n][(fl + (n >> 2)) & 15];
    unsigned int pw[8];
    #pragma unroll
    for (int q = 0; q < 8; ++q)
      pw[q] = (unsigned int)tmp[2 * q] | (((unsigned int)tmp[2 * q + 1]) << 16);
    uint4* dst = (uint4*)(o + (size_t)n * F_);
    dst[0] = make_uint4(pw[0], pw[1], pw[2], pw[3]);
    dst[1] = make_uint4(pw[4], pw[5], pw[6], pw[7]);
  }
}

// ---------------------------------------------------------------------------
extern "C" void kernel_launch(void* const* d_in, const int* in_sizes, int n_in,
                              void* d_out, int out_size, void* d_ws, size_t ws_size,
                              hipStream_t stream) {
  const float* x    = (const float*)d_in[0];
  const float* sw1f = (const float*)d_in[1];
  const float* sb1  = (const float*)d_in[2];
  const float* sw2f = (const float*)d_in[3];
  const float* sb2  = (const float*)d_in[4];
  const float* fw1f = (const float*)d_in[5];
  const float* fb1  = (const float*)d_in[6];
  const float* fw2f = (const float*)d_in[7];
  const float* fb2  = (const float*)d_in[8];
  float* outp = (float*)d_out;

  const size_t E = (size_t)B_ * F_ * N_;     // 67,108,864 elements
  // workspace layout (~730 MB)
  float*          xm  = (float*)d_ws;                     // E f32      [0, 256MB)
  unsigned short* xs  = (unsigned short*)(xm + E);        // E bf16     [256, 384)
  unsigned short* inv = xs + E;                           // E u16      [384, 512)
  unsigned short* wb  = inv + E;                          // weights bf16
  unsigned short* wsw1 = wb;                              // 8192*2048
  unsigned short* wsw2 = wsw1 + (size_t)HS_ * N_;         // 2048*8192
  unsigned short* wfw1 = wsw2 + (size_t)N_ * HS_;         // 4096*1024
  unsigned short* wfw2 = wfw1 + (size_t)HF_ * F_;         // 1024*4096
  unsigned short* Hc   = wfw2 + (size_t)OUT_ * HF_;       // 67.1M bf16 (134 MB) chunk hidden
  unsigned short* Y    = (unsigned short*)xm;             // reuse xm region (bf16)
  unsigned short* Y2   = xs;                              // reuse xs region

  // 0. convert weights f32 -> bf16
  f2bf_kernel<<<(HS_ * N_) / 2048, 256, 0, stream>>>(sw1f, wsw1, HS_ * N_);
  f2bf_kernel<<<(N_ * HS_) / 2048, 256, 0, stream>>>(sw2f, wsw2, N_ * HS_);
  f2bf_kernel<<<(HF_ * F_) / 2048, 256, 0, stream>>>(fw1f, wfw1, HF_ * F_);
  f2bf_kernel<<<(OUT_ * HF_) / 2048, 256, 0, stream>>>(fw2f, wfw2, OUT_ * HF_);

  // 1. transpose x -> xm (f32)
  transpose_xk<<<dim3(F_ / 64, N_ / 64, B_), 256, 0, stream>>>(x, xm);
  // 2. stable sort rows -> xs (bf16), inv (u16); one row per wave, 4 rows/block
  sort_kernel<<<dim3(B_ * F_ / 4), 256, 0, stream>>>(xm, xs, inv);

  // 3+4. sorted MLP, chunked over rows (4 x 8192 rows)
  for (int c = 0; c < 4; ++c) {
    const size_t ro = (size_t)c * 8192;
    gemm_bt<0><<<dim3(HS_ / 128, 8192 / 128), 256, 0, stream>>>(
        xs + ro * N_, wsw1, sb1, nullptr, Hc, HS_, N_);
    gemm_bt<1><<<dim3(N_ / 128, 8192 / 128), 256, 0, stream>>>(
        Hc, wsw2, sb2, xs + ro * N_, Y + ro * N_, N_, HS_);
  }

  // 5. Y2[b, inv[j], f] = Y[b, f, j]
  unpermute_kernel<<<dim3(B_ * (F_ / 16)), 256, 0, stream>>>(Y, inv, Y2);

  // 6+7. feature MLP, chunked over rows (4 x 16384 rows)
  for (int c = 0; c < 4; ++c) {
    const size_t ro = (size_t)c * 16384;
    gemm_bt<0><<<dim3(HF_ / 128, 16384 / 128), 256, 0, stream>>>(
        Y2 + ro * F_, wfw1, fb1, nullptr, Hc, HF_, F_);
    gemm_bt<2><<<dim3(OUT_ / 128, 16384 / 128), 256, 0, stream>>>(
        Hc, wfw2, fb2, nullptr, (void*)(outp + ro * OUT_), OUT_, HF_);
  }
}

// Round 3
// 5190.532 us; speedup vs baseline: 1.4437x; 1.1515x over previous
//
#include <hip/hip_runtime.h>
#include <hip/hip_bf16.h>
#include <stdint.h>

// Problem constants
#define B_   32
#define N_   2048   // n_stock
#define F_   1024   // in_features
#define HS_  8192   // 4*N
#define HF_  4096   // 4*F
#define OUT_ 1024

typedef __bf16 bf16x8 __attribute__((ext_vector_type(8)));
typedef float  f32x4  __attribute__((ext_vector_type(4)));
typedef unsigned long long u64;

__device__ __forceinline__ float bf2f(unsigned short u) {
  union { unsigned int i; float f; } c; c.i = ((unsigned int)u) << 16; return c.f;
}
__device__ __forceinline__ unsigned short f2bf(float f) {
  union { float f; unsigned int i; } c; c.f = f;
  unsigned int x = c.i;
  return (unsigned short)((x + 0x7FFFu + ((x >> 16) & 1u)) >> 16);  // RNE
}

// ---------------------------------------------------------------------------
// 0. f32 -> bf16 bulk convert (weights). n multiple of 8.
// ---------------------------------------------------------------------------
__global__ __launch_bounds__(256) void f2bf_kernel(
    const float* __restrict__ in, unsigned short* __restrict__ out, int n) {
  int i = (blockIdx.x * 256 + threadIdx.x) * 8;
  if (i >= n) return;
  const float4 a = ((const float4*)(in + i))[0];
  const float4 b = ((const float4*)(in + i))[1];
  unsigned int w0 = (unsigned int)f2bf(a.x) | ((unsigned int)f2bf(a.y) << 16);
  unsigned int w1 = (unsigned int)f2bf(a.z) | ((unsigned int)f2bf(a.w) << 16);
  unsigned int w2 = (unsigned int)f2bf(b.x) | ((unsigned int)f2bf(b.y) << 16);
  unsigned int w3 = (unsigned int)f2bf(b.z) | ((unsigned int)f2bf(b.w) << 16);
  *(uint4*)(out + i) = make_uint4(w0, w1, w2, w3);
}

// ---------------------------------------------------------------------------
// 1. Transpose x [B,N,F] -> xm [B,F,N]  (f32, LDS 64x64 tile, +1 pad)
// ---------------------------------------------------------------------------
__global__ __launch_bounds__(256) void transpose_xk(
    const float* __restrict__ x, float* __restrict__ xm) {
  __shared__ float tile[64][65];
  const int b  = blockIdx.z;
  const int n0 = blockIdx.y * 64;
  const int f0 = blockIdx.x * 64;
  const int tx = threadIdx.x & 63;
  const int ty = threadIdx.x >> 6;
  const float* xp = x + ((size_t)b * N_ + n0) * F_ + f0;
  #pragma unroll
  for (int r = 0; r < 16; ++r) {
    int n = ty + r * 4;
    tile[tx][n] = xp[(size_t)n * F_ + tx];   // tile[f][n]
  }
  __syncthreads();
  float* xmp = xm + ((size_t)b * F_ + f0) * N_ + n0;
  #pragma unroll
  for (int r = 0; r < 16; ++r) {
    int f = ty + r * 4;
    xmp[(size_t)f * N_ + tx] = tile[f][tx];
  }
}

// ---------------------------------------------------------------------------
// 2. Stable argsort per (b,f) row: ONE ROW PER WAVE, keys in registers.
//    (unchanged from passing R2 version)
// ---------------------------------------------------------------------------
template <int K, int J>
__device__ __forceinline__ void reg_stage_ct(u64 key[32]) {
  #pragma unroll
  for (int e = 0; e < 32; ++e) {
    if ((e & J) == 0) {
      const int f = e | J;
      const bool up = ((e & K) == 0);          // compile-time
      u64 a = key[e], b = key[f];
      if ((a > b) == up) { key[e] = b; key[f] = a; }
    }
  }
}

template <int J>
__device__ __forceinline__ void reg_stage_u(u64 key[32], bool up) {
  #pragma unroll
  for (int e = 0; e < 32; ++e) {
    if ((e & J) == 0) {
      const int f = e | J;
      u64 a = key[e], b = key[f];
      if ((a > b) == up) { key[e] = b; key[f] = a; }
    }
  }
}

__device__ __forceinline__ void xlane_stage(u64 key[32], int m, bool up) {
  const bool lower = ((__lane_id() & m) == 0);
  const bool keep_min = (up == lower);
  #pragma unroll
  for (int e = 0; e < 32; ++e) {
    u64 a = key[e];
    u64 b = __shfl_xor(a, m, 64);
    key[e] = ((a < b) == keep_min) ? a : b;
  }
}

__global__ __launch_bounds__(256, 4) void sort_kernel(
    const float* __restrict__ xm,
    unsigned short* __restrict__ xs,
    unsigned short* __restrict__ inv) {
  __shared__ __align__(16) unsigned int sbuf[4][N_];   // 32 KB, per-wave private
  const int t    = threadIdx.x;
  const int w    = t >> 6;
  const int lane = t & 63;
  const int row  = blockIdx.x * 4 + w;
  const size_t rb = (size_t)row * N_;
  const int i0   = lane * 32;

  u64 key[32];
  unsigned int vbf[16];
  const float4* rp = (const float4*)(xm + rb + i0);
  #pragma unroll
  for (int q = 0; q < 8; ++q) {
    const float4 v = rp[q];
    vbf[2 * q]     = (unsigned int)f2bf(v.x) | ((unsigned int)f2bf(v.y) << 16);
    vbf[2 * q + 1] = (unsigned int)f2bf(v.z) | ((unsigned int)f2bf(v.w) << 16);
    const float fv[4] = {v.x, v.y, v.z, v.w};
    #pragma unroll
    for (int e = 0; e < 4; ++e) {
      union { float f; unsigned int i; } c; c.f = fv[e];
      unsigned int m = (c.i & 0x80000000u) ? ~c.i : (c.i | 0x80000000u);
      key[q * 4 + e] = (((u64)m) << 32) | (u64)(i0 + q * 4 + e);
    }
  }

  reg_stage_ct<2, 1>(key);
  reg_stage_ct<4, 2>(key);  reg_stage_ct<4, 1>(key);
  reg_stage_ct<8, 4>(key);  reg_stage_ct<8, 2>(key);  reg_stage_ct<8, 1>(key);
  reg_stage_ct<16, 8>(key); reg_stage_ct<16, 4>(key);
  reg_stage_ct<16, 2>(key); reg_stage_ct<16, 1>(key);

  #pragma unroll 1
  for (int k = 32; k <= N_; k <<= 1) {
    const bool up = ((i0 & k) == 0);
    #pragma unroll 1
    for (int m = k >> 6; m >= 1; m >>= 1)    // empty for k=32
      xlane_stage(key, m, up);
    reg_stage_u<16>(key, up);
    reg_stage_u<8>(key, up);
    reg_stage_u<4>(key, up);
    reg_stage_u<2>(key, up);
    reg_stage_u<1>(key, up);
  }

  #pragma unroll
  for (int e = 0; e < 32; ++e) {
    const unsigned int orig  = (unsigned int)key[e] & (N_ - 1);
    const unsigned int val16 = (vbf[e >> 1] >> ((e & 1) * 16)) & 0xFFFFu;
    sbuf[w][orig] = (val16 << 16) | (unsigned int)(i0 + e);
  }

  const unsigned int* sb = sbuf[w];
  unsigned int* xs32  = (unsigned int*)(xs + rb);
  unsigned int* inv32 = (unsigned int*)(inv + rb);
  #pragma unroll
  for (int q = 0; q < 8; ++q) {
    const int w0 = q * 256 + lane * 4;
    const uint4 W = *(const uint4*)(sb + w0);
    uint2 xw, iw;
    xw.x = (W.x >> 16) | (W.y & 0xFFFF0000u);
    xw.y = (W.z >> 16) | (W.w & 0xFFFF0000u);
    iw.x = (W.x & 0xFFFFu) | (W.y << 16);
    iw.y = (W.z & 0xFFFFu) | (W.w << 16);
    *(uint2*)(xs32  + (w0 >> 1)) = xw;
    *(uint2*)(inv32 + (w0 >> 1)) = iw;
  }
}

// ---------------------------------------------------------------------------
// 3. NT GEMM, 256x256 tile, 8-phase-style schedule (m201 port, plain HIP):
//    C[M,N] = A[M,K] * Bt[N,K]^T, bf16 in, fp32 acc, 16x16x32 MFMA.
//    512 thr (8 waves, 2M x 4N), BK=64 split in two 32-col k-slabs,
//    double-buffered LDS (128 KiB), XOR-swizzled (colbyte ^= ((row>>1)&3)<<4,
//    applied to gload_lds GLOBAL source + ds_read addr; dest stays linear).
//    Per K-tile: 4 phases {ds_read frags | stage 1 half-tile (2 gload_lds) |
//    barrier | lgkmcnt(0) | setprio(1) 16 MFMA setprio(0)}; counted vmcnt(4)
//    only at ends of phases 1 and 3 (never 0 mid-loop).
//    Ledger (per-thread, 2 loads/unit): unit(T,p) staged in T's phase p holds
//    slab data for K-tile T+1 {p0:A-s0, p1:B-s0, p2:A-s1, p3:B-s1}.
//    end ph1 of T: outstanding (T-1,2)(T-1,3)(T,0)(T,1)=8 -> vmcnt(4)
//      completes (T-1,2)(T-1,3) = slab1 of tile T, read in ph2/3.  OK
//    end ph3 of T: outstanding (T,0..3)=8 -> vmcnt(4) completes (T,0)(T,1)
//      = slab0 of tile T+1, read in ph0/1 of T+1.  OK
//    Last tile: no staging issued -> use vmcnt(0) (tail, cheap).
//    EPI: 0 = bias+relu -> bf16, 1 = bias+skip(bf16) -> bf16, 2 = bias -> f32
// ---------------------------------------------------------------------------
#define GFENCE   asm volatile("" ::: "memory")
#define BAR      __builtin_amdgcn_s_barrier()
#define LGKM0    do { asm volatile("s_waitcnt lgkmcnt(0)" ::: "memory"); \
                      __builtin_amdgcn_sched_barrier(0); } while (0)
#define VMW(n)   asm volatile("s_waitcnt vmcnt(" #n ")" ::: "memory")

template <int EPI>
__global__ __launch_bounds__(512, 2) void gemm256(
    const unsigned short* __restrict__ A,
    const unsigned short* __restrict__ Bt,
    const float* __restrict__ bias,
    const unsigned short* __restrict__ skip,
    void* __restrict__ Cv,
    int N, int K) {
  // [buf][kslab][256 rows * 32 cols]  (16 KB per slab)
  __shared__ __align__(16) unsigned short As[2][2][256 * 32];
  __shared__ __align__(16) unsigned short Bs[2][2][256 * 32];
  const int n0   = blockIdx.x * 256;
  const int m0   = blockIdx.y * 256;
  const int t    = threadIdx.x;
  const int lane = t & 63;
  const int w    = t >> 6;         // 0..7
  const int wr   = w >> 2;         // 0..1  (M half)
  const int wc   = w & 3;          // 0..3  (N quarter)
  const int lr   = lane & 15;
  const int kg   = lane >> 4;      // 0..3

  // ds_read byte offset within a slab: row=lr(+16*i via frag base), col kg*16B,
  // swizzled: physical colbyte = logical ^ ((row>>1)&3)<<4 (frag-base-invariant)
  const int rdOff = lr * 64 + ((kg * 16) ^ (((lr >> 1) & 3) << 4));

  // staging source geometry: wave w, call q covers slab rows (w*2+q)*16..+15,
  // lane writes physical chunk P=(w*2+q)*1024 + lane*16 -> row=P>>6,
  // physical colbyte (lane&3)*16; logical = physical ^ swz(row) -> pre-swizzle src.
  int srow[2], scol[2];
  #pragma unroll
  for (int q = 0; q < 2; ++q) {
    const int row = (w * 2 + q) * 16 + (lane >> 2);
    const int cl  = ((lane & 3) * 16) ^ (((row >> 1) & 3) << 4);
    srow[q] = row;
    scol[q] = cl >> 1;             // element col within 32-col slab
  }
  const unsigned short* aB = A  + (size_t)m0 * K;
  const unsigned short* bB = Bt + (size_t)n0 * K;
  const unsigned short* aS[2] = { aB + (size_t)srow[0] * K + scol[0],
                                  aB + (size_t)srow[1] * K + scol[1] };
  const unsigned short* bS[2] = { bB + (size_t)srow[0] * K + scol[0],
                                  bB + (size_t)srow[1] * K + scol[1] };

#define STAGE_U(MAT, SRC, ks, nb, k1e)                                         \
  do {                                                                         \
    __builtin_amdgcn_global_load_lds(                                          \
        (const __attribute__((address_space(1))) void*)(SRC[0] + (k1e) + (ks) * 32), \
        (__attribute__((address_space(3))) void*)(&MAT[nb][ks][0] + (w * 2 + 0) * 512), \
        16, 0, 0);                                                             \
    __builtin_amdgcn_global_load_lds(                                          \
        (const __attribute__((address_space(1))) void*)(SRC[1] + (k1e) + (ks) * 32), \
        (__attribute__((address_space(3))) void*)(&MAT[nb][ks][0] + (w * 2 + 1) * 512), \
        16, 0, 0);                                                             \
  } while (0)

  f32x4 acc[8][4];
  #pragma unroll
  for (int i = 0; i < 8; ++i)
    #pragma unroll
    for (int j = 0; j < 4; ++j)
      acc[i][j] = (f32x4){0.f, 0.f, 0.f, 0.f};

  const int nt = K >> 6;

  // prologue: stage K-tile 0 into buf0 (order: A-s0, B-s0, A-s1, B-s1)
  STAGE_U(As, aS, 0, 0, 0);
  STAGE_U(Bs, bS, 0, 0, 0);
  STAGE_U(As, aS, 1, 0, 0);
  STAGE_U(Bs, bS, 1, 0, 0);
  VMW(4);                          // A-s0 + B-s0 landed
  BAR;

  int kt = 0;
  #pragma unroll 1
  for (int T = 0; T < nt; ++T, kt += 64) {
    const int bb = T & 1;
    const int nb = bb ^ 1;
    const bool nl = (T + 1 < nt);
    const int k1 = kt + 64;
    const char* Ab0 = (const char*)(&As[bb][0][0]) + wr * 8192 + rdOff;
    const char* Ab1 = (const char*)(&As[bb][1][0]) + wr * 8192 + rdOff;
    const char* Bb0 = (const char*)(&Bs[bb][0][0]) + wc * 4096 + rdOff;
    const char* Bb1 = (const char*)(&Bs[bb][1][0]) + wc * 4096 + rdOff;
    bf16x8 aF[4], bF[4];

    // ===== phase 0: kslab 0, M-frags 0-3 =====
    #pragma unroll
    for (int j = 0; j < 4; ++j) bF[j] = *(const bf16x8*)(Bb0 + j * 1024);
    #pragma unroll
    for (int i = 0; i < 4; ++i) aF[i] = *(const bf16x8*)(Ab0 + i * 1024);
    if (nl) STAGE_U(As, aS, 0, nb, k1);
    GFENCE; BAR; LGKM0;
    __builtin_amdgcn_s_setprio(1);
    #pragma unroll
    for (int i = 0; i < 4; ++i)
      #pragma unroll
      for (int j = 0; j < 4; ++j)
        acc[i][j] = __builtin_amdgcn_mfma_f32_16x16x32_bf16(aF[i], bF[j], acc[i][j], 0, 0, 0);
    __builtin_amdgcn_s_setprio(0);
    __builtin_amdgcn_sched_barrier(0);
    BAR;

    // ===== phase 1: kslab 0, M-frags 4-7 (bF reused) =====
    #pragma unroll
    for (int i = 0; i < 4; ++i) aF[i] = *(const bf16x8*)(Ab0 + (4 + i) * 1024);
    if (nl) STAGE_U(Bs, bS, 0, nb, k1);
    GFENCE; BAR; LGKM0;
    __builtin_amdgcn_s_setprio(1);
    #pragma unroll
    for (int i = 0; i < 4; ++i)
      #pragma unroll
      for (int j = 0; j < 4; ++j)
        acc[4 + i][j] = __builtin_amdgcn_mfma_f32_16x16x32_bf16(aF[i], bF[j], acc[4 + i][j], 0, 0, 0);
    __builtin_amdgcn_s_setprio(0);
    __builtin_amdgcn_sched_barrier(0);
    if (nl) { VMW(4); } else { VMW(0); }   // slab1 of tile T landed
    BAR;

    // ===== phase 2: kslab 1, M-frags 0-3 =====
    #pragma unroll
    for (int j = 0; j < 4; ++j) bF[j] = *(const bf16x8*)(Bb1 + j * 1024);
    #pragma unroll
    for (int i = 0; i < 4; ++i) aF[i] = *(const bf16x8*)(Ab1 + i * 1024);
    if (nl) STAGE_U(As, aS, 1, nb, k1);
    GFENCE; BAR; LGKM0;
    __builtin_amdgcn_s_setprio(1);
    #pragma unroll
    for (int i = 0; i < 4; ++i)
      #pragma unroll
      for (int j = 0; j < 4; ++j)
        acc[i][j] = __builtin_amdgcn_mfma_f32_16x16x32_bf16(aF[i], bF[j], acc[i][j], 0, 0, 0);
    __builtin_amdgcn_s_setprio(0);
    __builtin_amdgcn_sched_barrier(0);
    BAR;

    // ===== phase 3: kslab 1, M-frags 4-7 (bF reused) =====
    #pragma unroll
    for (int i = 0; i < 4; ++i) aF[i] = *(const bf16x8*)(Ab1 + (4 + i) * 1024);
    if (nl) STAGE_U(Bs, bS, 1, nb, k1);
    GFENCE; BAR; LGKM0;
    __builtin_amdgcn_s_setprio(1);
    #pragma unroll
    for (int i = 0; i < 4; ++i)
      #pragma unroll
      for (int j = 0; j < 4; ++j)
        acc[4 + i][j] = __builtin_amdgcn_mfma_f32_16x16x32_bf16(aF[i], bF[j], acc[4 + i][j], 0, 0, 0);
    __builtin_amdgcn_s_setprio(0);
    __builtin_amdgcn_sched_barrier(0);
    if (nl) { VMW(4); } else { VMW(0); }   // slab0 of tile T+1 landed
    BAR;
  }

  // epilogue: C/D layout col=lane&15, row=(lane>>4)*4+reg  [m89-verified]
  #pragma unroll
  for (int j = 0; j < 4; ++j) {
    const int gn = n0 + wc * 64 + j * 16 + lr;
    const float bvf = bias[gn];
    #pragma unroll
    for (int i = 0; i < 8; ++i) {
      const int gm = m0 + wr * 128 + i * 16 + kg * 4;
      #pragma unroll
      for (int r = 0; r < 4; ++r) {
        float v = acc[i][j][r] + bvf;
        if (EPI == 0) v = v > 0.f ? v : 0.f;
        const size_t off = (size_t)(gm + r) * N + gn;
        if (EPI == 1) v += bf2f(skip[off]);
        if (EPI == 2) ((float*)Cv)[off] = v;
        else          ((unsigned short*)Cv)[off] = f2bf(v);
      }
    }
  }
#undef STAGE_U
}

// ---------------------------------------------------------------------------
// 4. Unpermute + transpose: Y2[b, inv[b,f,j], f] = Y[b, f, j]   (bf16)
// ---------------------------------------------------------------------------
__global__ __launch_bounds__(256) void unpermute_kernel(
    const unsigned short* __restrict__ Y,
    const unsigned short* __restrict__ inv,
    unsigned short* __restrict__ Y2) {
  __shared__ unsigned short ot[N_][16];      // 64 KB, col swizzle (fl + (n>>2)) & 15
  const int b  = blockIdx.x >> 6;            // F/16 = 64 slabs per batch
  const int f0 = (blockIdx.x & 63) * 16;
  const int t  = threadIdx.x;
  const size_t rbase = ((size_t)b * F_ + f0) * N_;

  for (int fl = 0; fl < 16; ++fl) {
    const uint4 yv = ((const uint4*)(Y   + rbase + (size_t)fl * N_))[t];
    const uint4 iv = ((const uint4*)(inv + rbase + (size_t)fl * N_))[t];
    unsigned int yw[4] = {yv.x, yv.y, yv.z, yv.w};
    unsigned int iw[4] = {iv.x, iv.y, iv.z, iv.w};
    #pragma unroll
    for (int e = 0; e < 8; ++e) {
      unsigned short yy = (unsigned short)(yw[e >> 1] >> ((e & 1) * 16));
      int n = (int)(unsigned short)(iw[e >> 1] >> ((e & 1) * 16));
      ot[n][(fl + (n >> 2)) & 15] = yy;
    }
  }
  __syncthreads();
  unsigned short* o = Y2 + (size_t)b * N_ * F_ + f0;
  for (int it = 0; it < 8; ++it) {
    int n = it * 256 + t;
    unsigned short tmp[16];
    #pragma unroll
    for (int fl = 0; fl < 16; ++fl) tmp[fl] = ot[n][(fl + (n >> 2)) & 15];
    unsigned int pw[8];
    #pragma unroll
    for (int q = 0; q < 8; ++q)
      pw[q] = (unsigned int)tmp[2 * q] | (((unsigned int)tmp[2 * q + 1]) << 16);
    uint4* dst = (uint4*)(o + (size_t)n * F_);
    dst[0] = make_uint4(pw[0], pw[1], pw[2], pw[3]);
    dst[1] = make_uint4(pw[4], pw[5], pw[6], pw[7]);
  }
}

// ---------------------------------------------------------------------------
extern "C" void kernel_launch(void* const* d_in, const int* in_sizes, int n_in,
                              void* d_out, int out_size, void* d_ws, size_t ws_size,
                              hipStream_t stream) {
  const float* x    = (const float*)d_in[0];
  const float* sw1f = (const float*)d_in[1];
  const float* sb1  = (const float*)d_in[2];
  const float* sw2f = (const float*)d_in[3];
  const float* sb2  = (const float*)d_in[4];
  const float* fw1f = (const float*)d_in[5];
  const float* fb1  = (const float*)d_in[6];
  const float* fw2f = (const float*)d_in[7];
  const float* fb2  = (const float*)d_in[8];
  float* outp = (float*)d_out;

  const size_t E = (size_t)B_ * F_ * N_;     // 67,108,864 elements
  // workspace layout (~730 MB)
  float*          xm  = (float*)d_ws;                     // E f32      [0, 256MB)
  unsigned short* xs  = (unsigned short*)(xm + E);        // E bf16     [256, 384)
  unsigned short* inv = xs + E;                           // E u16      [384, 512)
  unsigned short* wb  = inv + E;                          // weights bf16
  unsigned short* wsw1 = wb;                              // 8192*2048
  unsigned short* wsw2 = wsw1 + (size_t)HS_ * N_;         // 2048*8192
  unsigned short* wfw1 = wsw2 + (size_t)N_ * HS_;         // 4096*1024
  unsigned short* wfw2 = wfw1 + (size_t)HF_ * F_;         // 1024*4096
  unsigned short* Hc   = wfw2 + (size_t)OUT_ * HF_;       // 67.1M bf16 (134 MB) chunk hidden
  unsigned short* Y    = (unsigned short*)xm;             // reuse xm region (bf16)
  unsigned short* Y2   = xs;                              // reuse xs region

  // 0. convert weights f32 -> bf16
  f2bf_kernel<<<(HS_ * N_) / 2048, 256, 0, stream>>>(sw1f, wsw1, HS_ * N_);
  f2bf_kernel<<<(N_ * HS_) / 2048, 256, 0, stream>>>(sw2f, wsw2, N_ * HS_);
  f2bf_kernel<<<(HF_ * F_) / 2048, 256, 0, stream>>>(fw1f, wfw1, HF_ * F_);
  f2bf_kernel<<<(OUT_ * HF_) / 2048, 256, 0, stream>>>(fw2f, wfw2, OUT_ * HF_);

  // 1. transpose x -> xm (f32)
  transpose_xk<<<dim3(F_ / 64, N_ / 64, B_), 256, 0, stream>>>(x, xm);
  // 2. stable sort rows -> xs (bf16), inv (u16); one row per wave, 4 rows/block
  sort_kernel<<<dim3(B_ * F_ / 4), 256, 0, stream>>>(xm, xs, inv);

  // 3+4. sorted MLP, chunked over rows (4 x 8192 rows)
  for (int c = 0; c < 4; ++c) {
    const size_t ro = (size_t)c * 8192;
    gemm256<0><<<dim3(HS_ / 256, 8192 / 256), 512, 0, stream>>>(
        xs + ro * N_, wsw1, sb1, nullptr, Hc, HS_, N_);
    gemm256<1><<<dim3(N_ / 256, 8192 / 256), 512, 0, stream>>>(
        Hc, wsw2, sb2, xs + ro * N_, Y + ro * N_, N_, HS_);
  }

  // 5. Y2[b, inv[j], f] = Y[b, f, j]
  unpermute_kernel<<<dim3(B_ * (F_ / 16)), 256, 0, stream>>>(Y, inv, Y2);

  // 6+7. feature MLP, chunked over rows (4 x 16384 rows)
  for (int c = 0; c < 4; ++c) {
    const size_t ro = (size_t)c * 16384;
    gemm256<0><<<dim3(HF_ / 256, 16384 / 256), 512, 0, stream>>>(
        Y2 + ro * F_, wfw1, fb1, nullptr, Hc, HF_, F_);
    gemm256<2><<<dim3(OUT_ / 256, 16384 / 256), 512, 0, stream>>>(
        Hc, wfw2, fb2, nullptr, (void*)(outp + ro * OUT_), OUT_, HF_);
  }
}